// Round 9
// baseline (453.427 us; speedup 1.0000x reference)
//
#include <hip/hip_runtime.h>

#define T_DIM 2048
#define B_DIM 4
#define S_DIM 2048
#define E_DIM 1024
#define H_NUM 16
#define HD    64
#define NH    64      // B*H
#define SP1   2049    // S+1 (bias token appended)
#define SPAD  2112    // 33*64, padded key length
#define NCHUNK 33
#define NTOKE ((size_t)T_DIM * B_DIM * E_DIM)   // 8192*1024

typedef short bf16x8 __attribute__((ext_vector_type(8)));
typedef short bf16x4 __attribute__((ext_vector_type(4)));
typedef float f32x4  __attribute__((ext_vector_type(4)));
typedef float f32x16 __attribute__((ext_vector_type(16)));
typedef unsigned int u32;

// log2(e): softmax done in exp2 domain; folded into Q projection scale.
#define QSCALE 0.18033688011112042f   // 0.125 * log2(e)

#if __has_builtin(__builtin_amdgcn_exp2f)
__device__ __forceinline__ float exp2_fast(float x) { return __builtin_amdgcn_exp2f(x); }
#else
__device__ __forceinline__ float exp2_fast(float x) { return __expf(x * 0.6931471805599453f); }
#endif

__device__ __forceinline__ unsigned short f2bf(float x) {
    union { float f; unsigned int u; } v; v.f = x;
    unsigned int r = v.u + 0x7FFFu + ((v.u >> 16) & 1u);   // RNE
    return (unsigned short)(r >> 16);
}

__device__ __forceinline__ u32 cvtpk_bf16(float lo, float hi) {
    u32 r;
    asm("v_cvt_pk_bf16_f32 %0, %1, %2" : "=v"(r) : "v"(lo), "v"(hi));
    return r;
}
__device__ __forceinline__ void plswap(u32& a, u32& b) {
    asm("v_permlane32_swap_b32 %0, %1" : "+v"(a), "+v"(b));
}

// async global->LDS, 16B per lane (m97 staging primitive)
__device__ __forceinline__ void load_lds16(const void* g, void* l) {
    __builtin_amdgcn_global_load_lds(
        (const __attribute__((address_space(1))) unsigned int*)g,
        (__attribute__((address_space(3))) unsigned int*)l, 16, 0, 0);
}

// ---------------------------------------------------------------------------
// One launch: y=0..2 inputs q|k|v -> bf16 [3][8192][1024]; y=3 all 4 weights.
// ---------------------------------------------------------------------------
__global__ __launch_bounds__(256)
void cvt_all(const float* __restrict__ q, const float* __restrict__ k,
             const float* __restrict__ v, const float* __restrict__ w0,
             const float* __restrict__ w1, const float* __restrict__ w2,
             const float* __restrict__ w3, short* __restrict__ indst,
             short* __restrict__ wdst)
{
    const int y = blockIdx.y;
    if (y < 3) {
        const float* src = (y == 0) ? q : (y == 1) ? k : v;
        short* d = indst + (size_t)y * NTOKE;
        const size_t i = (size_t)blockIdx.x * 256 + threadIdx.x;
        const float4* s = reinterpret_cast<const float4*>(src) + i * 2;
        float4 a = s[0], b = s[1];
        uint4 o;
        o.x = cvtpk_bf16(a.x, a.y); o.y = cvtpk_bf16(a.z, a.w);
        o.z = cvtpk_bf16(b.x, b.y); o.w = cvtpk_bf16(b.z, b.w);
        *(reinterpret_cast<uint4*>(d) + i) = o;
    } else {
        const size_t gi = (size_t)blockIdx.x * 256 + threadIdx.x;  // 0..1048575
        const size_t per = (size_t)E_DIM * E_DIM / 8;              // 131072
        if (gi >= 4 * per) return;
        const int wsel = (int)(gi / per);
        const size_t i = gi % per;
        const float* src = (wsel == 0) ? w0 : (wsel == 1) ? w1 : (wsel == 2) ? w2 : w3;
        short* d = wdst + (size_t)wsel * E_DIM * E_DIM;
        const float4* s = reinterpret_cast<const float4*>(src) + i * 2;
        float4 a = s[0], b = s[1];
        uint4 o;
        o.x = cvtpk_bf16(a.x, a.y); o.y = cvtpk_bf16(a.z, a.w);
        o.z = cvtpk_bf16(b.x, b.y); o.w = cvtpk_bf16(b.z, b.w);
        *(reinterpret_cast<uint4*>(d) + i) = o;
    }
}

// ---------------------------------------------------------------------------
// m97-structure bf16 GEMM (unchanged).
// ---------------------------------------------------------------------------
template<int MODE>
__global__ __launch_bounds__(256, 4)
void gemm_bf16(const short* __restrict__ Abase, const short* __restrict__ Wall,
               const float* __restrict__ biasAll, void* __restrict__ outp)
{
    __shared__ short As[128][64];
    __shared__ short Bs[128][64];
    const int bm = blockIdx.x, bn = blockIdx.y;
    const int z = (MODE == 0) ? blockIdx.z : 0;
    const short* Az = Abase + (MODE == 0 ? (size_t)z * NTOKE : 0);
    const short* W  = Wall + (size_t)z * E_DIM * E_DIM;
    const float* bias = biasAll + z * E_DIM;

    const int tid = threadIdx.x;
    const int l = tid & 63, w = tid >> 6;
    const int wr = w >> 1, wc = w & 1;
    const int lr = l & 15, lg = l >> 4;
    const int srow = tid >> 3, scol = (tid & 7) * 8;

    f32x4 acc[4][4] = {};

    for (int k0 = 0; k0 < E_DIM; k0 += 64) {
#pragma unroll
        for (int r = 0; r < 4; ++r) {
            const int row = r * 32 + srow;
            const short* ga;
            if (MODE == 3) {
                const int m = bm * 128 + row;
                ga = Az + ((size_t)((m & 3) * 16 + (k0 >> 6)) * T_DIM + (m >> 2)) * HD + scol;
            } else {
                ga = Az + (size_t)(bm * 128 + row) * E_DIM + k0 + scol;
            }
            load_lds16(ga, &As[row][scol]);
            load_lds16(W + (size_t)(bn * 128 + row) * E_DIM + k0 + scol, &Bs[row][scol]);
        }
        __syncthreads();

        __builtin_amdgcn_s_setprio(1);
#pragma unroll
        for (int c = 0; c < 2; ++c) {
            bf16x8 af[4], bf[4];
#pragma unroll
            for (int mi = 0; mi < 4; ++mi)
                af[mi] = *reinterpret_cast<const bf16x8*>(&As[wr * 64 + mi * 16 + lr][c * 32 + lg * 8]);
#pragma unroll
            for (int ni = 0; ni < 4; ++ni)
                bf[ni] = *reinterpret_cast<const bf16x8*>(&Bs[wc * 64 + ni * 16 + lr][c * 32 + lg * 8]);
#pragma unroll
            for (int mi = 0; mi < 4; ++mi)
#pragma unroll
                for (int ni = 0; ni < 4; ++ni)
                    acc[mi][ni] = __builtin_amdgcn_mfma_f32_16x16x32_bf16(
                        af[mi], bf[ni], acc[mi][ni], 0, 0, 0);
        }
        __builtin_amdgcn_s_setprio(0);
        __syncthreads();
    }

#pragma unroll
    for (int mi = 0; mi < 4; ++mi)
#pragma unroll
        for (int ni = 0; ni < 4; ++ni) {
            const int colg = bn * 128 + wc * 64 + ni * 16 + lr;
            const float bv = bias[colg];
#pragma unroll
            for (int r = 0; r < 4; ++r) {
                const int m = bm * 128 + wr * 64 + mi * 16 + lg * 4 + r;
                float v = acc[mi][ni][r] + bv;
                if (MODE == 3) {
                    ((float*)outp)[(size_t)m * E_DIM + colg] = v;
                } else {
                    if (z == 0) v *= QSCALE;
                    const int seq = m >> 2, b = m & 3;
                    const int head = colg >> 6, d = colg & 63;
                    const int sd = (z == 0) ? T_DIM : SPAD;
                    short* ob = (short*)outp;
                    if (z == 1) ob += (size_t)NH * T_DIM * HD;
                    else if (z == 2) ob += (size_t)NH * T_DIM * HD + (size_t)NH * SPAD * HD;
                    ob[((size_t)(b * 16 + head) * sd + seq) * HD + d] = (short)f2bf(v);
                }
            }
        }
}

// append bias_k/bias_v token at s=2048 (bf16), zero rows 2049..2111
__global__ void fill_kv_pad(short* __restrict__ k_h, short* __restrict__ v_h,
                            const float* __restrict__ bias_k,
                            const float* __restrict__ bias_v)
{
    const int d   = threadIdx.x;
    const int row = S_DIM + blockIdx.x;
    const int n   = blockIdx.y;
    short bk = 0, bv = 0;
    if (row == S_DIM) {
        bk = (short)f2bf(bias_k[(n & 15) * HD + d]);
        bv = (short)f2bf(bias_v[(n & 15) * HD + d]);
    }
    const size_t idx = ((size_t)n * SPAD + row) * HD + d;
    k_h[idx] = bk;
    v_h[idx] = bv;
}

// ---------------------------------------------------------------------------
// Swapped 32x32 MFMA flash attention, 8-wave blocks.
// Round-9: K lives in REGISTERS (A-fragment loaded straight from global,
// prefetched one chunk ahead) — no K LDS, no K ds_read conflicts. l back to
// tree+shfl (ones-MFMA reverted). -m_run stays folded into QK^T acc init.
// ---------------------------------------------------------------------------
__global__ __launch_bounds__(512, 4)
void attn_mfma(const short* __restrict__ q_h, const short* __restrict__ k_h,
               const short* __restrict__ v_h, short* __restrict__ o_h,
               float* __restrict__ m_arr, float* __restrict__ l_arr)
{
    __shared__ short VtD[2][64 * 64];   // 16 KB total

    const int id = blockIdx.x;
    const int xcd = id & 7, slot = id >> 3;        // slot 0..63
    const int n = xcd * 8 + (slot >> 3);
    const int q0 = (slot & 7) * 256;

    const int tid = threadIdx.x, l = tid & 63, w = tid >> 6;   // w 0..7
    const int ql = l & 31;
    const int hi = l >> 5;
    const int qrow = q0 + w * 32 + ql;

    const int sp = tid & 31, dq = tid >> 5;        // V staging coords

    const short* kbase = k_h + (size_t)n * SPAD * HD;
    const short* vbase = v_h + (size_t)n * SPAD * HD;

    // Q fragments (B operand): lane q = ql, k = sl*16 + hi*8 + j
    bf16x8 aq[4];
    {
        const short* qp = q_h + ((size_t)n * T_DIM + qrow) * HD + hi * 8;
#pragma unroll
        for (int sl = 0; sl < 4; ++sl) aq[sl] = *(const bf16x8*)(qp + sl * 16);
    }

    // K fragments (A operand) for current chunk: row=ql (+32), k=sl*16+hi*8+j
    bf16x8 kfA[4], kfB[4];
    {
        const short* kr = kbase + (size_t)ql * HD + hi * 8;
#pragma unroll
        for (int sl = 0; sl < 4; ++sl) {
            kfA[sl] = *(const bf16x8*)(kr + sl * 16);
            kfB[sl] = *(const bf16x8*)(kr + 32 * HD + sl * 16);
        }
    }

    // prologue: V chunk 0 -> regs -> LDS buf 0 (transposed, swizzled)
    bf16x4 pva = *(const bf16x4*)(vbase + (size_t)(2 * sp) * HD + dq * 4);
    bf16x4 pvb = *(const bf16x4*)(vbase + (size_t)(2 * sp + 1) * HD + dq * 4);
    {
        char* VtB = (char*)VtD[0];
#pragma unroll
        for (int j = 0; j < 4; ++j) {
            u32 pkd = (u32)(unsigned short)pva[j] | ((u32)(unsigned short)pvb[j] << 16);
            const int d = dq * 4 + j;
            *(u32*)(VtB + d * 128 + ((4 * sp) ^ ((d & 7) << 4))) = pkd;
        }
    }
    __syncthreads();

    float m_run = 0.0f;               // scores - m_run tracked inside acc
    float l_run = 0.0f;
    f32x16 accA, accB;
#pragma unroll
    for (int r = 0; r < 16; ++r) { accA[r] = 0.f; accB[r] = 0.f; }

    for (int kc = 0; kc < NCHUNK; ++kc) {
        const char* VtB = (const char*)VtD[kc & 1];
        const bool more = (kc + 1 < NCHUNK);
        const int s0n = (kc + 1) * 64;

        // ---- prefetch V for kc+1 (regs; written to LDS after PV) ----
        if (more) {
            pva = *(const bf16x4*)(vbase + (size_t)(s0n + 2 * sp) * HD + dq * 4);
            pvb = *(const bf16x4*)(vbase + (size_t)(s0n + 2 * sp + 1) * HD + dq * 4);
        }

        // ---- QK^T, acc pre-biased with -m_run => sc = s - m_run ----
        f32x16 sc0, sc1;
        const float nm = -m_run;
#pragma unroll
        for (int r = 0; r < 16; ++r) { sc0[r] = nm; sc1[r] = nm; }
        __builtin_amdgcn_s_setprio(1);
#pragma unroll
        for (int sl = 0; sl < 4; ++sl) {
            sc0 = __builtin_amdgcn_mfma_f32_32x32x16_bf16(kfA[sl], aq[sl], sc0, 0, 0, 0);
            sc1 = __builtin_amdgcn_mfma_f32_32x32x16_bf16(kfB[sl], aq[sl], sc1, 0, 0, 0);
        }
        __builtin_amdgcn_s_setprio(0);

        // ---- prefetch K for kc+1 (regs free after QK^T issue) ----
        if (more) {
            const short* kr = kbase + (size_t)(s0n + ql) * HD + hi * 8;
#pragma unroll
            for (int sl = 0; sl < 4; ++sl) {
                kfA[sl] = *(const bf16x8*)(kr + sl * 16);
                kfB[sl] = *(const bf16x8*)(kr + 32 * HD + sl * 16);
            }
        }

        const int s0 = kc * 64;
        if (s0 + 64 > SP1) {
#pragma unroll
            for (int r = 0; r < 16; ++r) {
                const int key = (r & 3) + 8 * (r >> 2) + 4 * hi;
                if (s0 + key >= SP1)      sc0[r] = -1e30f;
                if (s0 + 32 + key >= SP1) sc1[r] = -1e30f;
            }
        }

        // ---- defer-max on relative scores ----
        float mv[16];
#pragma unroll
        for (int r = 0; r < 16; ++r) mv[r] = fmaxf(sc0[r], sc1[r]);
#pragma unroll
        for (int s = 8; s > 0; s >>= 1)
#pragma unroll
            for (int r = 0; r < s; ++r) mv[r] = fmaxf(mv[r], mv[r + s]);
        const float mx = fmaxf(mv[0], __shfl_xor(mv[0], 32));   // max(s) - m_run
        if (!__all(mx <= 8.0f)) {
            const float sh = fmaxf(mx, 0.0f);
            const float fac = exp2_fast(-sh);
            l_run *= fac;
#pragma unroll
            for (int r = 0; r < 16; ++r) {
                accA[r] *= fac; accB[r] *= fac;
                sc0[r] -= sh;   sc1[r] -= sh;
            }
            m_run += sh;
        }
        float p0[16], p1[16];
#pragma unroll
        for (int r = 0; r < 16; ++r) p0[r] = exp2_fast(sc0[r]);
#pragma unroll
        for (int r = 0; r < 16; ++r) p1[r] = exp2_fast(sc1[r]);
        float sv[16];
#pragma unroll
        for (int r = 0; r < 16; ++r) sv[r] = p0[r] + p1[r];
#pragma unroll
        for (int s = 8; s > 0; s >>= 1)
#pragma unroll
            for (int r = 0; r < s; ++r) sv[r] += sv[r + s];
        l_run += sv[0] + __shfl_xor(sv[0], 32);

        // ---- P fragments in-register (cvt_pk + permlane32_swap) ----
        union PF { u32 u[4]; bf16x8 v; };
        PF pf0, pf1, pf2, pf3;
        {
            u32 a0 = cvtpk_bf16(p0[0], p0[1]),   b0 = cvtpk_bf16(p0[4], p0[5]);   plswap(a0, b0);
            u32 a1 = cvtpk_bf16(p0[2], p0[3]),   b1 = cvtpk_bf16(p0[6], p0[7]);   plswap(a1, b1);
            u32 a2 = cvtpk_bf16(p0[8], p0[9]),   b2 = cvtpk_bf16(p0[12], p0[13]); plswap(a2, b2);
            u32 a3 = cvtpk_bf16(p0[10], p0[11]), b3 = cvtpk_bf16(p0[14], p0[15]); plswap(a3, b3);
            pf0.u[0] = a0; pf0.u[1] = a1; pf0.u[2] = b0; pf0.u[3] = b1;
            pf1.u[0] = a2; pf1.u[1] = a3; pf1.u[2] = b2; pf1.u[3] = b3;
            u32 c0 = cvtpk_bf16(p1[0], p1[1]),   d0_ = cvtpk_bf16(p1[4], p1[5]);   plswap(c0, d0_);
            u32 c1 = cvtpk_bf16(p1[2], p1[3]),   d1_ = cvtpk_bf16(p1[6], p1[7]);   plswap(c1, d1_);
            u32 c2 = cvtpk_bf16(p1[8], p1[9]),   d2_ = cvtpk_bf16(p1[12], p1[13]); plswap(c2, d2_);
            u32 c3 = cvtpk_bf16(p1[10], p1[11]), d3_ = cvtpk_bf16(p1[14], p1[15]); plswap(c3, d3_);
            pf2.u[0] = c0; pf2.u[1] = c1; pf2.u[2] = d0_; pf2.u[3] = d1_;
            pf3.u[0] = c2; pf3.u[1] = c3; pf3.u[2] = d2_; pf3.u[3] = d3_;
        }

        // ---- PV: O^T += Vt @ P ----
        __builtin_amdgcn_s_setprio(1);
#pragma unroll
        for (int ksl = 0; ksl < 4; ++ksl) {
            const int cb = ((ksl * 32) + hi * 16) ^ ((ql & 7) << 4);
            bf16x8 vf0 = *(const bf16x8*)(VtB + ql * 128 + cb);
            bf16x8 vf1 = *(const bf16x8*)(VtB + (32 + ql) * 128 + cb);
            const bf16x8 pv = (ksl == 0) ? pf0.v : (ksl == 1) ? pf1.v : (ksl == 2) ? pf2.v : pf3.v;
            accA = __builtin_amdgcn_mfma_f32_32x32x16_bf16(vf0, pv, accA, 0, 0, 0);
            accB = __builtin_amdgcn_mfma_f32_32x32x16_bf16(vf1, pv, accB, 0, 0, 0);
        }
        __builtin_amdgcn_s_setprio(0);

        // ---- write prefetched V to other buffer, single barrier ----
        if (more) {
            char* VtN = (char*)VtD[(kc & 1) ^ 1];
#pragma unroll
            for (int j = 0; j < 4; ++j) {
                u32 pkd = (u32)(unsigned short)pva[j] | ((u32)(unsigned short)pvb[j] << 16);
                const int d = dq * 4 + j;
                *(u32*)(VtN + d * 128 + ((4 * sp) ^ ((d & 7) << 4))) = pkd;
            }
            __syncthreads();
        }
    }

    const float il = 1.0f / l_run;
    short* orow = o_h + ((size_t)n * T_DIM + qrow) * HD;
#pragma unroll
    for (int rq = 0; rq < 4; ++rq) {
        uint2 st;
        st.x = cvtpk_bf16(accA[rq * 4 + 0] * il, accA[rq * 4 + 1] * il);
        st.y = cvtpk_bf16(accA[rq * 4 + 2] * il, accA[rq * 4 + 3] * il);
        *(uint2*)(orow + rq * 8 + hi * 4) = st;
        uint2 st2;
        st2.x = cvtpk_bf16(accB[rq * 4 + 0] * il, accB[rq * 4 + 1] * il);
        st2.y = cvtpk_bf16(accB[rq * 4 + 2] * il, accB[rq * 4 + 3] * il);
        *(uint2*)(orow + 32 + rq * 8 + hi * 4) = st2;
    }
    if (hi == 0) {
        m_arr[n * T_DIM + qrow] = m_run;
        l_arr[n * T_DIM + qrow] = l_run;
    }
}

// ---------------------------------------------------------------------------
// avg_weights: -mq folded into acc init (unchanged from round 8).
// ---------------------------------------------------------------------------
__global__ __launch_bounds__(256)
void colsum_mfma(const short* __restrict__ q_h, const short* __restrict__ k_h,
                 const float* __restrict__ m_arr, const float* __restrict__ l_arr,
                 float* __restrict__ avg_out)
{
    __shared__ short Qs[2][64][72];
    __shared__ float msh[2][64];
    __shared__ float lih[2][64];

    const int id = blockIdx.x;
    const int xcd = id & 7, slot = id >> 3;        // slot 0..263
    const int n = xcd * 8 + slot / 33;
    const int s0 = (slot % 33) * 64;

    const int tid = threadIdx.x, l = tid & 63, w = tid >> 6;
    const int lr = l & 15, lg = l >> 4;
    const int qr = tid >> 3, qcg = tid & 7;

    const short* qbase = q_h + (size_t)n * T_DIM * HD;

    bf16x8 ak[2];
#pragma unroll
    for (int c = 0; c < 2; ++c)
        ak[c] = *reinterpret_cast<const bf16x8*>(
            k_h + ((size_t)n * SPAD + s0 + w * 16 + lr) * HD + c * 32 + lg * 8);

    bf16x8 qa = *(const bf16x8*)(qbase + (size_t)qr * HD + qcg * 8);
    bf16x8 qb = *(const bf16x8*)(qbase + (size_t)(32 + qr) * HD + qcg * 8);
    float mlv = 0.f;
    if (tid < 64) mlv = m_arr[n * T_DIM + tid];
    else if (tid < 128) mlv = l_arr[n * T_DIM + tid - 64];
    *(bf16x8*)&Qs[0][qr][qcg * 8] = qa;
    *(bf16x8*)&Qs[0][32 + qr][qcg * 8] = qb;
    if (tid < 64) msh[0][tid] = mlv;
    else if (tid < 128) lih[0][tid - 64] = 1.0f / mlv;
    __syncthreads();

    float csum[4] = {0.f, 0.f, 0.f, 0.f};

    for (int it = 0; it < T_DIM / 64; ++it) {
        const int buf = it & 1;
        const bool more = (it + 1 < T_DIM / 64);
        if (more) {
            const int qo = (it + 1) * 64;
            qa = *(const bf16x8*)(qbase + (size_t)(qo + qr) * HD + qcg * 8);
            qb = *(const bf16x8*)(qbase + (size_t)(qo + 32 + qr) * HD + qcg * 8);
            if (tid < 64) mlv = m_arr[n * T_DIM + qo + tid];
            else if (tid < 128) mlv = l_arr[n * T_DIM + qo + tid - 64];
        }
        __builtin_amdgcn_s_setprio(1);
#pragma unroll
        for (int qt = 0; qt < 4; ++qt) {
            bf16x8 bq0 = *reinterpret_cast<const bf16x8*>(&Qs[buf][qt * 16 + lr][lg * 8]);
            bf16x8 bq1 = *reinterpret_cast<const bf16x8*>(&Qs[buf][qt * 16 + lr][32 + lg * 8]);
            const float mq = msh[buf][qt * 16 + lr];
            const float lq = lih[buf][qt * 16 + lr];
            f32x4 z;
#pragma unroll
            for (int r = 0; r < 4; ++r) z[r] = -mq;
            z = __builtin_amdgcn_mfma_f32_16x16x32_bf16(ak[0], bq0, z, 0, 0, 0);
            z = __builtin_amdgcn_mfma_f32_16x16x32_bf16(ak[1], bq1, z, 0, 0, 0);
#pragma unroll
            for (int r = 0; r < 4; ++r)
                csum[r] += exp2_fast(z[r]) * lq;
        }
        __builtin_amdgcn_s_setprio(0);
        if (more) {
            *(bf16x8*)&Qs[buf ^ 1][qr][qcg * 8] = qa;
            *(bf16x8*)&Qs[buf ^ 1][32 + qr][qcg * 8] = qb;
            if (tid < 64) msh[buf ^ 1][tid] = mlv;
            else if (tid < 128) lih[buf ^ 1][tid - 64] = 1.0f / mlv;
            __syncthreads();
        }
    }

#pragma unroll
    for (int r = 0; r < 4; ++r) {
        float v = csum[r];
        v += __shfl_xor(v, 1, 16);
        v += __shfl_xor(v, 2, 16);
        v += __shfl_xor(v, 4, 16);
        v += __shfl_xor(v, 8, 16);
        if (lr == 0) {
            const int key = s0 + w * 16 + lg * 4 + r;
            if (key < SP1) avg_out[(size_t)n * SP1 + key] = v * 0.0625f;
        }
    }
}

// ---------------------------------------------------------------------------
extern "C" void kernel_launch(void* const* d_in, const int* in_sizes, int n_in,
                              void* d_out, int out_size, void* d_ws, size_t ws_size,
                              hipStream_t stream)
{
    const float* query   = (const float*)d_in[0];
    const float* key     = (const float*)d_in[1];
    const float* value   = (const float*)d_in[2];
    const float* wq      = (const float*)d_in[3];
    const float* wk      = (const float*)d_in[4];
    const float* wv      = (const float*)d_in[5];
    const float* in_bias = (const float*)d_in[6];
    const float* bias_k  = (const float*)d_in[7];
    const float* bias_v  = (const float*)d_in[8];
    const float* wo      = (const float*)d_in[9];
    const float* out_b   = (const float*)d_in[10];
    float* out = (float*)d_out;

    short* wqb    = (short*)d_ws;                        // [4][1024][1024] bf16
    short* wob    = wqb + (size_t)3 * E_DIM * E_DIM;
    short* qkv_bf = wqb + (size_t)4 * E_DIM * E_DIM;     // [3][8192][1024] bf16
    short* q_h = qkv_bf + 3 * NTOKE;                     // [64][2048][64]
    short* k_h = q_h + (size_t)NH * T_DIM * HD;          // [64][2112][64]
    short* v_h = k_h + (size_t)NH * SPAD * HD;           // [64][2112][64]
    short* o_h = v_h + (size_t)NH * SPAD * HD;           // [64][2048][64]
    float* m_arr = (float*)(o_h + (size_t)NH * T_DIM * HD);
    float* l_arr = m_arr + (size_t)NH * T_DIM;

    const dim3 blk(256);
    hipLaunchKernelGGL(cvt_all, dim3(4096, 4), blk, 0, stream,
                       query, key, value, wq, wk, wv, wo, qkv_bf, wqb);

    hipLaunchKernelGGL((gemm_bf16<0>), dim3(64, 8, 3), blk, 0, stream,
                       qkv_bf, wqb, in_bias, (void*)q_h);
    hipLaunchKernelGGL(fill_kv_pad, dim3(SPAD - S_DIM, NH), dim3(64), 0, stream,
                       k_h, v_h, bias_k, bias_v);
    hipLaunchKernelGGL(attn_mfma, dim3(512), dim3(512), 0, stream,
                       q_h, k_h, v_h, o_h, m_arr, l_arr);
    hipLaunchKernelGGL(colsum_mfma, dim3(2112), blk, 0, stream,
                       q_h, k_h, m_arr, l_arr, out + (size_t)T_DIM * B_DIM * E_DIM);
    hipLaunchKernelGGL((gemm_bf16<3>), dim3(64, 8), blk, 0, stream,
                       o_h, wob, out_b, (void*)out);
}

// Round 10
// 280.998 us; speedup vs baseline: 1.6136x; 1.6136x over previous
//
#include <hip/hip_runtime.h>

#define T_DIM 2048
#define B_DIM 4
#define S_DIM 2048
#define E_DIM 1024
#define H_NUM 16
#define HD    64
#define NH    64      // B*H
#define SP1   2049    // S+1 (bias token appended)
#define SPAD  2112    // 33*64, padded key length
#define NCHUNK 33
#define NTOKE ((size_t)T_DIM * B_DIM * E_DIM)   // 8192*1024

typedef short bf16x8 __attribute__((ext_vector_type(8)));
typedef short bf16x4 __attribute__((ext_vector_type(4)));
typedef float f32x4  __attribute__((ext_vector_type(4)));
typedef float f32x16 __attribute__((ext_vector_type(16)));
typedef unsigned int u32;

// log2(e): softmax done in exp2 domain; folded into Q projection scale.
#define QSCALE 0.18033688011112042f   // 0.125 * log2(e)

#if __has_builtin(__builtin_amdgcn_exp2f)
__device__ __forceinline__ float exp2_fast(float x) { return __builtin_amdgcn_exp2f(x); }
#else
__device__ __forceinline__ float exp2_fast(float x) { return __expf(x * 0.6931471805599453f); }
#endif

__device__ __forceinline__ unsigned short f2bf(float x) {
    union { float f; unsigned int u; } v; v.f = x;
    unsigned int r = v.u + 0x7FFFu + ((v.u >> 16) & 1u);   // RNE
    return (unsigned short)(r >> 16);
}

__device__ __forceinline__ u32 cvtpk_bf16(float lo, float hi) {
    u32 r;
    asm("v_cvt_pk_bf16_f32 %0, %1, %2" : "=v"(r) : "v"(lo), "v"(hi));
    return r;
}
__device__ __forceinline__ void plswap(u32& a, u32& b) {
    asm("v_permlane32_swap_b32 %0, %1" : "+v"(a), "+v"(b));
}

// async global->LDS, 16B per lane (m97 staging primitive)
__device__ __forceinline__ void load_lds16(const void* g, void* l) {
    __builtin_amdgcn_global_load_lds(
        (const __attribute__((address_space(1))) unsigned int*)g,
        (__attribute__((address_space(3))) unsigned int*)l, 16, 0, 0);
}

// ---------------------------------------------------------------------------
// One launch: y=0..2 inputs q|k|v -> bf16; y=3 weights + kv pad fill.
// ---------------------------------------------------------------------------
__global__ __launch_bounds__(256)
void cvt_all(const float* __restrict__ q, const float* __restrict__ k,
             const float* __restrict__ v, const float* __restrict__ w0,
             const float* __restrict__ w1, const float* __restrict__ w2,
             const float* __restrict__ w3, short* __restrict__ indst,
             short* __restrict__ wdst, short* __restrict__ k_h,
             short* __restrict__ v_h, const float* __restrict__ bias_k,
             const float* __restrict__ bias_v)
{
    const int y = blockIdx.y;
    if (y < 3) {
        const float* src = (y == 0) ? q : (y == 1) ? k : v;
        short* d = indst + (size_t)y * NTOKE;
        const size_t i = (size_t)blockIdx.x * 256 + threadIdx.x;
        const float4* s = reinterpret_cast<const float4*>(src) + i * 2;
        float4 a = s[0], b = s[1];
        uint4 o;
        o.x = cvtpk_bf16(a.x, a.y); o.y = cvtpk_bf16(a.z, a.w);
        o.z = cvtpk_bf16(b.x, b.y); o.w = cvtpk_bf16(b.z, b.w);
        *(reinterpret_cast<uint4*>(d) + i) = o;
    } else {
        const size_t gi = (size_t)blockIdx.x * 256 + threadIdx.x;
        const size_t per = (size_t)E_DIM * E_DIM / 8;              // 131072
        if (gi < 4 * per) {
            const int wsel = (int)(gi / per);
            const size_t i = gi % per;
            const float* src = (wsel == 0) ? w0 : (wsel == 1) ? w1 : (wsel == 2) ? w2 : w3;
            short* d = wdst + (size_t)wsel * E_DIM * E_DIM;
            const float4* s = reinterpret_cast<const float4*>(src) + i * 2;
            float4 a = s[0], b = s[1];
            uint4 o;
            o.x = cvtpk_bf16(a.x, a.y); o.y = cvtpk_bf16(a.z, a.w);
            o.z = cvtpk_bf16(b.x, b.y); o.w = cvtpk_bf16(b.z, b.w);
            *(reinterpret_cast<uint4*>(d) + i) = o;
        } else {
            // kv pad fill: rows S_DIM..SPAD-1 of k_h/v_h (disjoint from GEMM output)
            const size_t fi = gi - 4 * per;                        // 0..262143
            if (fi < (size_t)(SPAD - S_DIM) * NH * HD) {
                const int d   = (int)(fi & 63);
                const int row = (int)((fi >> 6) & 63);             // 0..63 -> S_DIM+row
                const int n   = (int)(fi >> 12);                   // 0..63
                short bk = 0, bv = 0;
                if (row == 0) {
                    bk = (short)f2bf(bias_k[(n & 15) * HD + d]);
                    bv = (short)f2bf(bias_v[(n & 15) * HD + d]);
                }
                const size_t idx = ((size_t)n * SPAD + S_DIM + row) * HD + d;
                k_h[idx] = bk;
                v_h[idx] = bv;
            }
        }
    }
}

// ---------------------------------------------------------------------------
// m97-structure bf16 GEMM (unchanged).
// ---------------------------------------------------------------------------
template<int MODE>
__global__ __launch_bounds__(256, 4)
void gemm_bf16(const short* __restrict__ Abase, const short* __restrict__ Wall,
               const float* __restrict__ biasAll, void* __restrict__ outp)
{
    __shared__ short As[128][64];
    __shared__ short Bs[128][64];
    const int bm = blockIdx.x, bn = blockIdx.y;
    const int z = (MODE == 0) ? blockIdx.z : 0;
    const short* Az = Abase + (MODE == 0 ? (size_t)z * NTOKE : 0);
    const short* W  = Wall + (size_t)z * E_DIM * E_DIM;
    const float* bias = biasAll + z * E_DIM;

    const int tid = threadIdx.x;
    const int l = tid & 63, w = tid >> 6;
    const int wr = w >> 1, wc = w & 1;
    const int lr = l & 15, lg = l >> 4;
    const int srow = tid >> 3, scol = (tid & 7) * 8;

    f32x4 acc[4][4] = {};

    for (int k0 = 0; k0 < E_DIM; k0 += 64) {
#pragma unroll
        for (int r = 0; r < 4; ++r) {
            const int row = r * 32 + srow;
            const short* ga;
            if (MODE == 3) {
                const int m = bm * 128 + row;
                ga = Az + ((size_t)((m & 3) * 16 + (k0 >> 6)) * T_DIM + (m >> 2)) * HD + scol;
            } else {
                ga = Az + (size_t)(bm * 128 + row) * E_DIM + k0 + scol;
            }
            load_lds16(ga, &As[row][scol]);
            load_lds16(W + (size_t)(bn * 128 + row) * E_DIM + k0 + scol, &Bs[row][scol]);
        }
        __syncthreads();

        __builtin_amdgcn_s_setprio(1);
#pragma unroll
        for (int c = 0; c < 2; ++c) {
            bf16x8 af[4], bf[4];
#pragma unroll
            for (int mi = 0; mi < 4; ++mi)
                af[mi] = *reinterpret_cast<const bf16x8*>(&As[wr * 64 + mi * 16 + lr][c * 32 + lg * 8]);
#pragma unroll
            for (int ni = 0; ni < 4; ++ni)
                bf[ni] = *reinterpret_cast<const bf16x8*>(&Bs[wc * 64 + ni * 16 + lr][c * 32 + lg * 8]);
#pragma unroll
            for (int mi = 0; mi < 4; ++mi)
#pragma unroll
                for (int ni = 0; ni < 4; ++ni)
                    acc[mi][ni] = __builtin_amdgcn_mfma_f32_16x16x32_bf16(
                        af[mi], bf[ni], acc[mi][ni], 0, 0, 0);
        }
        __builtin_amdgcn_s_setprio(0);
        __syncthreads();
    }

#pragma unroll
    for (int mi = 0; mi < 4; ++mi)
#pragma unroll
        for (int ni = 0; ni < 4; ++ni) {
            const int colg = bn * 128 + wc * 64 + ni * 16 + lr;
            const float bv = bias[colg];
#pragma unroll
            for (int r = 0; r < 4; ++r) {
                const int m = bm * 128 + wr * 64 + mi * 16 + lg * 4 + r;
                float v = acc[mi][ni][r] + bv;
                if (MODE == 3) {
                    ((float*)outp)[(size_t)m * E_DIM + colg] = v;
                } else {
                    if (z == 0) v *= QSCALE;
                    const int seq = m >> 2, b = m & 3;
                    const int head = colg >> 6, d = colg & 63;
                    const int sd = (z == 0) ? T_DIM : SPAD;
                    short* ob = (short*)outp;
                    if (z == 1) ob += (size_t)NH * T_DIM * HD;
                    else if (z == 2) ob += (size_t)NH * T_DIM * HD + (size_t)NH * SPAD * HD;
                    ob[((size_t)(b * 16 + head) * sd + seq) * HD + d] = (short)f2bf(v);
                }
            }
        }
}

// ---------------------------------------------------------------------------
// Swapped 32x32 MFMA flash attention, 8-wave blocks, K+V in dbuf LDS with
// reg-prefetch (round-7 proven structure) + -m_run folded into acc init.
// ---------------------------------------------------------------------------
__global__ __launch_bounds__(512, 4)
void attn_mfma(const short* __restrict__ q_h, const short* __restrict__ k_h,
               const short* __restrict__ v_h, short* __restrict__ o_h,
               float* __restrict__ m_arr, float* __restrict__ l_arr)
{
    __shared__ short KsD[2][64 * 64];
    __shared__ short VtD[2][64 * 64];

    const int id = blockIdx.x;
    const int xcd = id & 7, slot = id >> 3;        // slot 0..63
    const int n = xcd * 8 + (slot >> 3);
    const int q0 = (slot & 7) * 256;

    const int tid = threadIdx.x, l = tid & 63, w = tid >> 6;   // w 0..7
    const int ql = l & 31;
    const int hi = l >> 5;
    const int qrow = q0 + w * 32 + ql;

    const int krow = tid >> 3, kcg = tid & 7;
    const int kswz = (kcg * 16) ^ ((krow & 7) << 4);
    const int sp = tid & 31, dq = tid >> 5;

    const short* kbase = k_h + (size_t)n * SPAD * HD;
    const short* vbase = v_h + (size_t)n * SPAD * HD;

    bf16x8 aq0, aq1, aq2, aq3;
    {
        const short* qp = q_h + ((size_t)n * T_DIM + qrow) * HD + hi * 8;
        aq0 = *(const bf16x8*)(qp);
        aq1 = *(const bf16x8*)(qp + 16);
        aq2 = *(const bf16x8*)(qp + 32);
        aq3 = *(const bf16x8*)(qp + 48);
    }

    bf16x8 pk  = *(const bf16x8*)(kbase + (size_t)krow * HD + kcg * 8);
    bf16x4 pva = *(const bf16x4*)(vbase + (size_t)(2 * sp) * HD + dq * 4);
    bf16x4 pvb = *(const bf16x4*)(vbase + (size_t)(2 * sp + 1) * HD + dq * 4);
    {
        char* KsB = (char*)KsD[0];
        char* VtB = (char*)VtD[0];
        *(bf16x8*)(KsB + krow * 128 + kswz) = pk;
#pragma unroll
        for (int j = 0; j < 4; ++j) {
            u32 pkd = (u32)(unsigned short)pva[j] | ((u32)(unsigned short)pvb[j] << 16);
            const int d = dq * 4 + j;
            *(u32*)(VtB + d * 128 + ((4 * sp) ^ ((d & 7) << 4))) = pkd;
        }
    }
    __syncthreads();

    float m_run = 0.0f;               // scores - m_run tracked inside acc
    float l_run = 0.0f;
    f32x16 accA, accB;
#pragma unroll
    for (int r = 0; r < 16; ++r) { accA[r] = 0.f; accB[r] = 0.f; }

    for (int kc = 0; kc < NCHUNK; ++kc) {
        const char* KsB = (const char*)KsD[kc & 1];
        const char* VtB = (const char*)VtD[kc & 1];
        const bool more = (kc + 1 < NCHUNK);

        // ---- prefetch chunk kc+1 into regs (hidden under compute) ----
        if (more) {
            const int s0n = (kc + 1) * 64;
            pk  = *(const bf16x8*)(kbase + (size_t)(s0n + krow) * HD + kcg * 8);
            pva = *(const bf16x4*)(vbase + (size_t)(s0n + 2 * sp) * HD + dq * 4);
            pvb = *(const bf16x4*)(vbase + (size_t)(s0n + 2 * sp + 1) * HD + dq * 4);
        }

        // ---- QK^T, acc pre-biased with -m_run => sc = s - m_run ----
        f32x16 sc0, sc1;
        const float nm = -m_run;
#pragma unroll
        for (int r = 0; r < 16; ++r) { sc0[r] = nm; sc1[r] = nm; }
        __builtin_amdgcn_s_setprio(1);
#pragma unroll
        for (int sl = 0; sl < 4; ++sl) {
            const int cb = ((sl * 32) + hi * 16) ^ ((ql & 7) << 4);
            bf16x8 kf0 = *(const bf16x8*)(KsB + ql * 128 + cb);
            bf16x8 kf1 = *(const bf16x8*)(KsB + (32 + ql) * 128 + cb);
            bf16x8 qf = (sl == 0) ? aq0 : (sl == 1) ? aq1 : (sl == 2) ? aq2 : aq3;
            sc0 = __builtin_amdgcn_mfma_f32_32x32x16_bf16(kf0, qf, sc0, 0, 0, 0);
            sc1 = __builtin_amdgcn_mfma_f32_32x32x16_bf16(kf1, qf, sc1, 0, 0, 0);
        }
        __builtin_amdgcn_s_setprio(0);

        const int s0 = kc * 64;
        if (s0 + 64 > SP1) {
#pragma unroll
            for (int r = 0; r < 16; ++r) {
                const int key = (r & 3) + 8 * (r >> 2) + 4 * hi;
                if (s0 + key >= SP1)      sc0[r] = -1e30f;
                if (s0 + 32 + key >= SP1) sc1[r] = -1e30f;
            }
        }

        // ---- defer-max on relative scores ----
        float mv[16];
#pragma unroll
        for (int r = 0; r < 16; ++r) mv[r] = fmaxf(sc0[r], sc1[r]);
#pragma unroll
        for (int s = 8; s > 0; s >>= 1)
#pragma unroll
            for (int r = 0; r < s; ++r) mv[r] = fmaxf(mv[r], mv[r + s]);
        const float mx = fmaxf(mv[0], __shfl_xor(mv[0], 32));   // max(s) - m_run
        if (!__all(mx <= 8.0f)) {
            const float sh = fmaxf(mx, 0.0f);
            const float fac = exp2_fast(-sh);
            l_run *= fac;
#pragma unroll
            for (int r = 0; r < 16; ++r) {
                accA[r] *= fac; accB[r] *= fac;
                sc0[r] -= sh;   sc1[r] -= sh;
            }
            m_run += sh;
        }
        float p0[16], p1[16];
#pragma unroll
        for (int r = 0; r < 16; ++r) p0[r] = exp2_fast(sc0[r]);
#pragma unroll
        for (int r = 0; r < 16; ++r) p1[r] = exp2_fast(sc1[r]);
        float sv[16];
#pragma unroll
        for (int r = 0; r < 16; ++r) sv[r] = p0[r] + p1[r];
#pragma unroll
        for (int s = 8; s > 0; s >>= 1)
#pragma unroll
            for (int r = 0; r < s; ++r) sv[r] += sv[r + s];
        l_run += sv[0] + __shfl_xor(sv[0], 32);

        // ---- P fragments in-register (cvt_pk + permlane32_swap) ----
        union PF { u32 u[4]; bf16x8 v; };
        PF pf0, pf1, pf2, pf3;
        {
            u32 a0 = cvtpk_bf16(p0[0], p0[1]),   b0 = cvtpk_bf16(p0[4], p0[5]);   plswap(a0, b0);
            u32 a1 = cvtpk_bf16(p0[2], p0[3]),   b1 = cvtpk_bf16(p0[6], p0[7]);   plswap(a1, b1);
            u32 a2 = cvtpk_bf16(p0[8], p0[9]),   b2 = cvtpk_bf16(p0[12], p0[13]); plswap(a2, b2);
            u32 a3 = cvtpk_bf16(p0[10], p0[11]), b3 = cvtpk_bf16(p0[14], p0[15]); plswap(a3, b3);
            pf0.u[0] = a0; pf0.u[1] = a1; pf0.u[2] = b0; pf0.u[3] = b1;
            pf1.u[0] = a2; pf1.u[1] = a3; pf1.u[2] = b2; pf1.u[3] = b3;
            u32 c0 = cvtpk_bf16(p1[0], p1[1]),   d0_ = cvtpk_bf16(p1[4], p1[5]);   plswap(c0, d0_);
            u32 c1 = cvtpk_bf16(p1[2], p1[3]),   d1_ = cvtpk_bf16(p1[6], p1[7]);   plswap(c1, d1_);
            u32 c2 = cvtpk_bf16(p1[8], p1[9]),   d2_ = cvtpk_bf16(p1[12], p1[13]); plswap(c2, d2_);
            u32 c3 = cvtpk_bf16(p1[10], p1[11]), d3_ = cvtpk_bf16(p1[14], p1[15]); plswap(c3, d3_);
            pf2.u[0] = c0; pf2.u[1] = c1; pf2.u[2] = d0_; pf2.u[3] = d1_;
            pf3.u[0] = c2; pf3.u[1] = c3; pf3.u[2] = d2_; pf3.u[3] = d3_;
        }

        // ---- PV: O^T += Vt @ P ----
        __builtin_amdgcn_s_setprio(1);
#pragma unroll
        for (int ksl = 0; ksl < 4; ++ksl) {
            const int cb = ((ksl * 32) + hi * 16) ^ ((ql & 7) << 4);
            bf16x8 vf0 = *(const bf16x8*)(VtB + ql * 128 + cb);
            bf16x8 vf1 = *(const bf16x8*)(VtB + (32 + ql) * 128 + cb);
            const bf16x8 pv = (ksl == 0) ? pf0.v : (ksl == 1) ? pf1.v : (ksl == 2) ? pf2.v : pf3.v;
            accA = __builtin_amdgcn_mfma_f32_32x32x16_bf16(vf0, pv, accA, 0, 0, 0);
            accB = __builtin_amdgcn_mfma_f32_32x32x16_bf16(vf1, pv, accB, 0, 0, 0);
        }
        __builtin_amdgcn_s_setprio(0);

        // ---- write prefetched chunk to other buffer, single barrier ----
        if (more) {
            char* KsN = (char*)KsD[(kc & 1) ^ 1];
            char* VtN = (char*)VtD[(kc & 1) ^ 1];
            *(bf16x8*)(KsN + krow * 128 + kswz) = pk;
#pragma unroll
            for (int j = 0; j < 4; ++j) {
                u32 pkd = (u32)(unsigned short)pva[j] | ((u32)(unsigned short)pvb[j] << 16);
                const int d = dq * 4 + j;
                *(u32*)(VtN + d * 128 + ((4 * sp) ^ ((d & 7) << 4))) = pkd;
            }
            __syncthreads();
        }
    }

    const float il = 1.0f / l_run;
    short* orow = o_h + ((size_t)n * T_DIM + qrow) * HD;
#pragma unroll
    for (int rq = 0; rq < 4; ++rq) {
        uint2 st;
        st.x = cvtpk_bf16(accA[rq * 4 + 0] * il, accA[rq * 4 + 1] * il);
        st.y = cvtpk_bf16(accA[rq * 4 + 2] * il, accA[rq * 4 + 3] * il);
        *(uint2*)(orow + rq * 8 + hi * 4) = st;
        uint2 st2;
        st2.x = cvtpk_bf16(accB[rq * 4 + 0] * il, accB[rq * 4 + 1] * il);
        st2.y = cvtpk_bf16(accB[rq * 4 + 2] * il, accB[rq * 4 + 3] * il);
        *(uint2*)(orow + 32 + rq * 8 + hi * 4) = st2;
    }
    if (hi == 0) {
        m_arr[n * T_DIM + qrow] = m_run;
        l_arr[n * T_DIM + qrow] = l_run;
    }
}

// ---------------------------------------------------------------------------
// avg_weights: -mq folded into acc init (round-8 form, kept).
// ---------------------------------------------------------------------------
__global__ __launch_bounds__(256)
void colsum_mfma(const short* __restrict__ q_h, const short* __restrict__ k_h,
                 const float* __restrict__ m_arr, const float* __restrict__ l_arr,
                 float* __restrict__ avg_out)
{
    __shared__ short Qs[2][64][72];
    __shared__ float msh[2][64];
    __shared__ float lih[2][64];

    const int id = blockIdx.x;
    const int xcd = id & 7, slot = id >> 3;        // slot 0..263
    const int n = xcd * 8 + slot / 33;
    const int s0 = (slot % 33) * 64;

    const int tid = threadIdx.x, l = tid & 63, w = tid >> 6;
    const int lr = l & 15, lg = l >> 4;
    const int qr = tid >> 3, qcg = tid & 7;

    const short* qbase = q_h + (size_t)n * T_DIM * HD;

    bf16x8 ak[2];
#pragma unroll
    for (int c = 0; c < 2; ++c)
        ak[c] = *reinterpret_cast<const bf16x8*>(
            k_h + ((size_t)n * SPAD + s0 + w * 16 + lr) * HD + c * 32 + lg * 8);

    bf16x8 qa = *(const bf16x8*)(qbase + (size_t)qr * HD + qcg * 8);
    bf16x8 qb = *(const bf16x8*)(qbase + (size_t)(32 + qr) * HD + qcg * 8);
    float mlv = 0.f;
    if (tid < 64) mlv = m_arr[n * T_DIM + tid];
    else if (tid < 128) mlv = l_arr[n * T_DIM + tid - 64];
    *(bf16x8*)&Qs[0][qr][qcg * 8] = qa;
    *(bf16x8*)&Qs[0][32 + qr][qcg * 8] = qb;
    if (tid < 64) msh[0][tid] = mlv;
    else if (tid < 128) lih[0][tid - 64] = 1.0f / mlv;
    __syncthreads();

    float csum[4] = {0.f, 0.f, 0.f, 0.f};

    for (int it = 0; it < T_DIM / 64; ++it) {
        const int buf = it & 1;
        const bool more = (it + 1 < T_DIM / 64);
        if (more) {
            const int qo = (it + 1) * 64;
            qa = *(const bf16x8*)(qbase + (size_t)(qo + qr) * HD + qcg * 8);
            qb = *(const bf16x8*)(qbase + (size_t)(qo + 32 + qr) * HD + qcg * 8);
            if (tid < 64) mlv = m_arr[n * T_DIM + qo + tid];
            else if (tid < 128) mlv = l_arr[n * T_DIM + qo + tid - 64];
        }
        __builtin_amdgcn_s_setprio(1);
#pragma unroll
        for (int qt = 0; qt < 4; ++qt) {
            bf16x8 bq0 = *reinterpret_cast<const bf16x8*>(&Qs[buf][qt * 16 + lr][lg * 8]);
            bf16x8 bq1 = *reinterpret_cast<const bf16x8*>(&Qs[buf][qt * 16 + lr][32 + lg * 8]);
            const float mq = msh[buf][qt * 16 + lr];
            const float lq = lih[buf][qt * 16 + lr];
            f32x4 z;
#pragma unroll
            for (int r = 0; r < 4; ++r) z[r] = -mq;
            z = __builtin_amdgcn_mfma_f32_16x16x32_bf16(ak[0], bq0, z, 0, 0, 0);
            z = __builtin_amdgcn_mfma_f32_16x16x32_bf16(ak[1], bq1, z, 0, 0, 0);
#pragma unroll
            for (int r = 0; r < 4; ++r)
                csum[r] += exp2_fast(z[r]) * lq;
        }
        __builtin_amdgcn_s_setprio(0);
        if (more) {
            *(bf16x8*)&Qs[buf ^ 1][qr][qcg * 8] = qa;
            *(bf16x8*)&Qs[buf ^ 1][32 + qr][qcg * 8] = qb;
            if (tid < 64) msh[buf ^ 1][tid] = mlv;
            else if (tid < 128) lih[buf ^ 1][tid - 64] = 1.0f / mlv;
            __syncthreads();
        }
    }

#pragma unroll
    for (int r = 0; r < 4; ++r) {
        float v = csum[r];
        v += __shfl_xor(v, 1, 16);
        v += __shfl_xor(v, 2, 16);
        v += __shfl_xor(v, 4, 16);
        v += __shfl_xor(v, 8, 16);
        if (lr == 0) {
            const int key = s0 + w * 16 + lg * 4 + r;
            if (key < SP1) avg_out[(size_t)n * SP1 + key] = v * 0.0625f;
        }
    }
}

// ---------------------------------------------------------------------------
extern "C" void kernel_launch(void* const* d_in, const int* in_sizes, int n_in,
                              void* d_out, int out_size, void* d_ws, size_t ws_size,
                              hipStream_t stream)
{
    const float* query   = (const float*)d_in[0];
    const float* key     = (const float*)d_in[1];
    const float* value   = (const float*)d_in[2];
    const float* wq      = (const float*)d_in[3];
    const float* wk      = (const float*)d_in[4];
    const float* wv      = (const float*)d_in[5];
    const float* in_bias = (const float*)d_in[6];
    const float* bias_k  = (const float*)d_in[7];
    const float* bias_v  = (const float*)d_in[8];
    const float* wo      = (const float*)d_in[9];
    const float* out_b   = (const float*)d_in[10];
    float* out = (float*)d_out;

    short* wqb    = (short*)d_ws;                        // [4][1024][1024] bf16
    short* wob    = wqb + (size_t)3 * E_DIM * E_DIM;
    short* qkv_bf = wqb + (size_t)4 * E_DIM * E_DIM;     // [3][8192][1024] bf16
    short* q_h = qkv_bf + 3 * NTOKE;                     // [64][2048][64]
    short* k_h = q_h + (size_t)NH * T_DIM * HD;          // [64][2112][64]
    short* v_h = k_h + (size_t)NH * SPAD * HD;           // [64][2112][64]
    short* o_h = v_h + (size_t)NH * SPAD * HD;           // [64][2048][64]
    float* m_arr = (float*)(o_h + (size_t)NH * T_DIM * HD);
    float* l_arr = m_arr + (size_t)NH * T_DIM;

    const dim3 blk(256);
    hipLaunchKernelGGL(cvt_all, dim3(4096, 4), blk, 0, stream,
                       query, key, value, wq, wk, wv, wo, qkv_bf, wqb,
                       k_h, v_h, bias_k, bias_v);

    hipLaunchKernelGGL((gemm_bf16<0>), dim3(64, 8, 3), blk, 0, stream,
                       qkv_bf, wqb, in_bias, (void*)q_h);
    hipLaunchKernelGGL(attn_mfma, dim3(512), dim3(512), 0, stream,
                       q_h, k_h, v_h, o_h, m_arr, l_arr);
    hipLaunchKernelGGL(colsum_mfma, dim3(2112), blk, 0, stream,
                       q_h, k_h, m_arr, l_arr, out + (size_t)T_DIM * B_DIM * E_DIM);
    hipLaunchKernelGGL((gemm_bf16<3>), dim3(64, 8), blk, 0, stream,
                       o_h, wob, out_b, (void*)out);
}